// Round 8
// baseline (415.707 us; speedup 1.0000x reference)
//
#include <hip/hip_runtime.h>
#include <stdint.h>

#define B_ 1024
#define D_ 784
#define H_ 1024
#define BH_ (B_ * H_)
#define LOG2E 1.4426950408889634f

// nade_main v6: 1 wave = 1 row-segment, 16 h/lane, fp32 pre-paired plane VW
// (v5 layout, verified). R7 evidence: latency-bound (VALUBusy 65% @ 2.5
// waves/SIMD, busy-equiv falls across versions while time pinned at 250us).
// Fix: 8 segments -> 8192 waves = 2048 blocks = exactly 8 blocks/CU (32
// waves/CU potential, 3.2x TLP). Same per-elem issue cost; steps/wave halve.
// No explicit prefetch (compiler sinks it; TLP hides latency instead).
// Tree restructured per-pair to cap liveness (~60 VGPR) under the
// __launch_bounds__(256,8) 64-VGPR cap. WRITE_SIZE = spill tripwire.
// XCD k serves segment k&(nseg-1): VWf slice ~0.8MB L2-resident, lockstep.
// G [nseg-1][B][H] fp32; ws guard: if ws_size < 8-seg need, fall back to the
// verified 4-seg geometry (same kernels, table-driven).
// ws: VWf [788][2048] f32 6.46 MB | G [7][B][H] fp32 29.4 MB (8-seg)

typedef float v2f __attribute__((ext_vector_type(2)));

__constant__ int SEGTAB4[5] = {0, 200, 392, 592, 784};
__constant__ int SEGTAB8[9] = {0, 96, 192, 288, 384, 480, 584, 688, 784};

// position of (i, h, part) in VWf; part 0 = V, 1 = -W*log2e  (v5 layout, verified)
// plane = part*4 + ((h&7)>>1); within plane: lane*4 + (h&1)*2 + (h>>9)
__device__ __forceinline__ size_t vw_idx(int i, int h, int part) {
    return (size_t)i * 2048 + (part * 4 + ((h & 7) >> 1)) * 256
         + ((h & 511) >> 3) * 4 + (h & 1) * 2 + (h >> 9);
}

// ---------- fat prep ----------
__global__ __launch_bounds__(256) void prep(const float* __restrict__ V,
                                            const float* __restrict__ W,
                                            const float* __restrict__ px,
                                            float* __restrict__ VWf,
                                            float* __restrict__ G,
                                            int nseg) {
    __shared__ float smem[1056];
    const int t = threadIdx.x;
    const int* st = (nseg == 8) ? SEGTAB8 : SEGTAB4;

    if (blockIdx.x < 800) {
        int i0 = (blockIdx.x % 25) * 32;
        int h0 = (blockIdx.x / 25) * 32;
        int tx = t & 31, ty = t >> 5;   // 32 x 8
        // V: read coalesced over h, write paired-scatter
#pragma unroll
        for (int j = 0; j < 4; ++j) {
            int i = i0 + ty + j * 8;
            if (i < D_)
                VWf[vw_idx(i, h0 + tx, 0)] = V[(size_t)i * H_ + h0 + tx];
        }
        // W: read coalesced over i, transpose via smem, store NEGATED * log2e
#pragma unroll
        for (int j = 0; j < 4; ++j) {
            int h = h0 + ty + j * 8;
            int i = i0 + tx;
            float v = 0.f;
            if (i < D_) v = W[(size_t)h * D_ + i] * -LOG2E;
            smem[(ty + j * 8) * 33 + tx] = v;
        }
        __syncthreads();
#pragma unroll
        for (int j = 0; j < 4; ++j) {
            int i = i0 + ty + j * 8;
            if (i < D_)
                VWf[vw_idx(i, h0 + tx, 1)] = smem[tx * 33 + ty + j * 8];
        }
    } else {
        float* xs = smem;          // [8][64]
        float* ws = smem + 512;    // [8][64]
        int idx = blockIdx.x - 800;
        int r   = idx >> 8;                       // 0..nseg-2
        int b0  = (idx & 15) * 64;
        int h0  = ((idx >> 4) & 15) * 64;
        int j0s = st[r], j1s = st[r + 1];

        const int tb = t >> 4, th = t & 15;       // 16x16, each 4b x 4h
        float acc[4][4];
#pragma unroll
        for (int bi = 0; bi < 4; ++bi)
#pragma unroll
            for (int hh = 0; hh < 4; ++hh) acc[bi][hh] = 0.f;

        const int xb = t >> 3;                    // 0..31
        const int xj = t & 7;                     // 0..7
        const int wh = t >> 1, wj = (t & 1) * 4;  // for t < 128

        for (int j0 = j0s; j0 < j1s; j0 += 8) {   // range lengths all %8 == 0
            float xv0 = px[(size_t)(b0 + xb) * D_ + j0 + xj];
            float xv1 = px[(size_t)(b0 + 32 + xb) * D_ + j0 + xj];
            float4 wv = make_float4(0, 0, 0, 0);
            if (t < 128) wv = *(const float4*)(W + (size_t)(h0 + wh) * D_ + j0 + wj);
            __syncthreads();
            xs[xj * 64 + xb]      = xv0;
            xs[xj * 64 + 32 + xb] = xv1;
            if (t < 128) {
                ws[(wj + 0) * 64 + wh] = wv.x * LOG2E;   // G stays POSITIVE domain
                ws[(wj + 1) * 64 + wh] = wv.y * LOG2E;
                ws[(wj + 2) * 64 + wh] = wv.z * LOG2E;
                ws[(wj + 3) * 64 + wh] = wv.w * LOG2E;
            }
            __syncthreads();
#pragma unroll
            for (int jj = 0; jj < 8; ++jj) {
                float4 xq = *(float4*)&xs[jj * 64 + tb * 4];
                float4 wq = *(float4*)&ws[jj * 64 + th * 4];
                float xa[4] = {xq.x, xq.y, xq.z, xq.w};
                float wa[4] = {wq.x, wq.y, wq.z, wq.w};
#pragma unroll
                for (int bi = 0; bi < 4; ++bi)
#pragma unroll
                    for (int hh = 0; hh < 4; ++hh)
                        acc[bi][hh] = fmaf(xa[bi], wa[hh], acc[bi][hh]);
            }
        }
        float* dst = G + (size_t)r * BH_;
#pragma unroll
        for (int bi = 0; bi < 4; ++bi) {
            float4 o = make_float4(acc[bi][0], acc[bi][1], acc[bi][2], acc[bi][3]);
            *(float4*)(dst + (size_t)(b0 + tb * 4 + bi) * H_ + h0 + th * 4) = o;
        }
    }
}

// ---------- DPP reduce: full 64-lane sum into lane 63 ----------
template <int CTRL>
__device__ __forceinline__ float dpp_add(float p) {
    int s = __builtin_amdgcn_update_dpp(0, __float_as_int(p), CTRL, 0xf, 0xf, true);
    return p + __int_as_float(s);
}
__device__ __forceinline__ float reduce64(float p) {
    p = dpp_add<0x111>(p);   // row_shr:1
    p = dpp_add<0x112>(p);   // row_shr:2
    p = dpp_add<0x114>(p);   // row_shr:4
    p = dpp_add<0x118>(p);   // row_shr:8
    p = dpp_add<0x142>(p);   // row_bcast:15 -> lane31 = sum(0..31), lane63 = sum(32..63)
    p = dpp_add<0x143>(p);   // row_bcast:31 -> lane63 = sum(0..63)
    return p;
}

// ---------- main scan v6: 1 wave = 1 row-segment, TLP-hidden latency ----------
__global__ __launch_bounds__(256, 8) void nade_main(
    const float* __restrict__ px,            // [B, D]
    const float* __restrict__ c,             // [H]
    const float* __restrict__ VWf,           // fp32 paired plane images
    const float* __restrict__ G,             // [nseg-1][B][H] (log2 domain, positive)
    const float* __restrict__ bias,          // [D]
    float* __restrict__ out,                 // [B, D]
    int nseg, int sshift)
{
    const int lane = threadIdx.x & 63;
    const int wid  = threadIdx.x >> 6;
    const int bid  = blockIdx.x;
    const int s    = bid & (nseg - 1);       // xcd = bid&7 -> one segment per XCD
    const int rb   = bid >> sshift;          // 0..255
    const int row  = rb * 4 + wid;

    const int* st = (nseg == 8) ? SEGTAB8 : SEGTAB4;
    const int i0s = st[s], i1s = st[s + 1];

    const int hA = lane * 8;
    const int hB = 512 + hA;

    // An = NEGATED log2-domain accumulator: sigma = 1/(1+2^An)
    v2f An[8];
    {
        float4 c0 = *(const float4*)(c + hA);
        float4 c1 = *(const float4*)(c + hA + 4);
        float4 c2 = *(const float4*)(c + hB);
        float4 c3 = *(const float4*)(c + hB + 4);
        An[0].x = -c0.x * LOG2E; An[0].y = -c2.x * LOG2E;
        An[1].x = -c0.y * LOG2E; An[1].y = -c2.y * LOG2E;
        An[2].x = -c0.z * LOG2E; An[2].y = -c2.z * LOG2E;
        An[3].x = -c0.w * LOG2E; An[3].y = -c2.w * LOG2E;
        An[4].x = -c1.x * LOG2E; An[4].y = -c3.x * LOG2E;
        An[5].x = -c1.y * LOG2E; An[5].y = -c3.y * LOG2E;
        An[6].x = -c1.z * LOG2E; An[6].y = -c3.z * LOG2E;
        An[7].x = -c1.w * LOG2E; An[7].y = -c3.w * LOG2E;
        for (int r = 0; r < s; ++r) {
            const float* gp = G + (size_t)r * BH_ + (size_t)row * H_;
            float4 g0 = *(const float4*)(gp + hA);
            float4 g1 = *(const float4*)(gp + hA + 4);
            float4 g2 = *(const float4*)(gp + hB);
            float4 g3 = *(const float4*)(gp + hB + 4);
            An[0].x -= g0.x; An[0].y -= g2.x;
            An[1].x -= g0.y; An[1].y -= g2.y;
            An[2].x -= g0.z; An[2].y -= g2.z;
            An[3].x -= g0.w; An[3].y -= g2.w;
            An[4].x -= g1.x; An[4].y -= g3.x;
            An[5].x -= g1.y; An[5].y -= g3.y;
            An[6].x -= g1.z; An[6].y -= g3.z;
            An[7].x -= g1.w; An[7].y -= g3.w;
        }
    }

    const float* xp = px + (size_t)row * D_;
    // image = 2048 floats; lane's plane-m slice at m*256 + lane*4 floats
    const float* vp = VWf + (size_t)i0s * 2048 + lane * 4;

    const v2f one = {1.f, 1.f};
    const v2f clamp15 = {15.f, 15.f};

    for (int ib = i0s; ib < i1s; ib += 4) {     // all segment lengths %4 == 0
        float4 xq = *(const float4*)(xp + ib);  // wave-uniform
        float xa[4] = {xq.x, xq.y, xq.z, xq.w};
        float pr[4];
#pragma unroll
        for (int j = 0; j < 4; ++j) {
            v2f xiv; xiv.x = xa[j]; xiv.y = xa[j];
            v2f a[4], qp[4];
#pragma unroll
            for (int kk = 0; kk < 4; ++kk) {    // pairs (2kk, 2kk+1): low liveness
                float4 Vq = *(const float4*)(vp + kk * 256);
                float4 Wq = *(const float4*)(vp + 1024 + kk * 256);
                const v2f* vv = (const v2f*)&Vq;
                const v2f* ww = (const v2f*)&Wq;
                const int k0 = 2 * kk, k1 = k0 + 1;
                v2f m0 = __builtin_elementwise_min(clamp15, An[k0]);
                v2f m1 = __builtin_elementwise_min(clamp15, An[k1]);
                v2f e0, e1;
                e0.x = __builtin_amdgcn_exp2f(m0.x);
                e0.y = __builtin_amdgcn_exp2f(m0.y);
                e1.x = __builtin_amdgcn_exp2f(m1.x);
                e1.y = __builtin_amdgcn_exp2f(m1.y);
                v2f q0 = one + e0;
                v2f q1 = one + e1;
                An[k0] = ww[0] * xiv + An[k0];  // v_pk_fma_f32 (W pre-negated)
                An[k1] = ww[1] * xiv + An[k1];
                a[kk]  = vv[0] * q1 + vv[1] * q0;
                qp[kk] = q0 * q1;
            }
            vp += 2048;
            v2f n0123 = a[0] * qp[1] + a[1] * qp[0];
            v2f n4567 = a[2] * qp[3] + a[3] * qp[2];
            v2f q0123 = qp[0] * qp[1], q4567 = qp[2] * qp[3];
            v2f d = q0123 * q4567;
            v2f n = n0123 * q4567 + n4567 * q0123;
            float p = fmaf(n.x, __builtin_amdgcn_rcpf(d.x),
                           n.y * __builtin_amdgcn_rcpf(d.y));
            pr[j] = reduce64(p);
        }
        float4 b4 = *(const float4*)(bias + ib);
        if (lane == 63) {
            float4 o = make_float4(pr[0] + b4.x, pr[1] + b4.y, pr[2] + b4.z, pr[3] + b4.w);
            *(float4*)(out + (size_t)row * D_ + ib) = o;
        }
    }
}

extern "C" void kernel_launch(void* const* d_in, const int* in_sizes, int n_in,
                              void* d_out, int out_size, void* d_ws, size_t ws_size,
                              hipStream_t stream) {
    const float* px   = (const float*)d_in[0];  // [B, D]
    const float* W    = (const float*)d_in[1];  // [H, D]
    const float* c    = (const float*)d_in[2];  // [H]
    const float* V    = (const float*)d_in[3];  // [D, H]
    const float* bias = (const float*)d_in[4];  // [D]
    float* out = (float*)d_out;                 // [B, D]

    float* VWf = (float*)d_ws;                                // 788*2048 f32 = 6.46 MB
    float* G   = (float*)((char*)d_ws + (size_t)788 * 8192);

    // 8-seg needs VWf + 7 G planes = 35.8 MB; fall back to verified 4-seg if tight
    const size_t need8 = (size_t)788 * 8192 + (size_t)7 * BH_ * 4;
    const int nseg   = (ws_size >= need8) ? 8 : 4;
    const int sshift = (nseg == 8) ? 3 : 2;

    // 800 pack blocks + (nseg-1) x 256 G-matmul blocks
    prep<<<dim3(800 + (nseg - 1) * 256), 256, 0, stream>>>(V, W, px, VWf, G, nseg);

    // nseg x 256 blocks x 4 waves; wave = (row, segment)
    nade_main<<<dim3(nseg * 256), 256, 0, stream>>>(px, c, VWf, G, bias, out, nseg, sshift);
}

// Round 9
// 340.715 us; speedup vs baseline: 1.2201x; 1.2201x over previous
//
#include <hip/hip_runtime.h>
#include <stdint.h>

#define B_ 1024
#define D_ 784
#define H_ 1024
#define BH_ (B_ * H_)
#define LOG2E 1.4426950408889634f

// nade_main v7 = v6 body DESPILLED: __launch_bounds__(256,4) (128-VGPR cap).
// R8: (256,8)'s 64-VGPR cap spilled An/tree state (WRITE 78MB, R2 signature).
// NEVER use (256,8) with this body family.
// Structure: 1 wave = 1 row-segment, 16 h/lane, fp32 pre-paired plane VW
// (v5 layout, verified), 8 segments -> 2048 blocks; per-pair tree keeps
// liveness low; TLP (not explicit prefetch) hides latency.
// Diagnostic fork: if time ~180-200us -> latency theory confirmed; if flat
// ~250us -> operand-delivery (L2 BW) bound -> next: row-paired v2f.
// XCD k serves segment k&7: VWf slice ~0.8MB L2-resident, lockstep streams.
// G [nseg-1][B][H] fp32; ws guard falls back to verified 4-seg geometry.
// ws: VWf [788][2048] f32 6.46 MB | G [7][B][H] fp32 29.4 MB (8-seg)

typedef float v2f __attribute__((ext_vector_type(2)));

__constant__ int SEGTAB4[5] = {0, 200, 392, 592, 784};
__constant__ int SEGTAB8[9] = {0, 96, 192, 288, 384, 480, 584, 688, 784};

// position of (i, h, part) in VWf; part 0 = V, 1 = -W*log2e  (v5 layout, verified)
// plane = part*4 + ((h&7)>>1); within plane: lane*4 + (h&1)*2 + (h>>9)
__device__ __forceinline__ size_t vw_idx(int i, int h, int part) {
    return (size_t)i * 2048 + (part * 4 + ((h & 7) >> 1)) * 256
         + ((h & 511) >> 3) * 4 + (h & 1) * 2 + (h >> 9);
}

// ---------- fat prep ----------
__global__ __launch_bounds__(256) void prep(const float* __restrict__ V,
                                            const float* __restrict__ W,
                                            const float* __restrict__ px,
                                            float* __restrict__ VWf,
                                            float* __restrict__ G,
                                            int nseg) {
    __shared__ float smem[1056];
    const int t = threadIdx.x;
    const int* st = (nseg == 8) ? SEGTAB8 : SEGTAB4;

    if (blockIdx.x < 800) {
        int i0 = (blockIdx.x % 25) * 32;
        int h0 = (blockIdx.x / 25) * 32;
        int tx = t & 31, ty = t >> 5;   // 32 x 8
        // V: read coalesced over h, write paired-scatter
#pragma unroll
        for (int j = 0; j < 4; ++j) {
            int i = i0 + ty + j * 8;
            if (i < D_)
                VWf[vw_idx(i, h0 + tx, 0)] = V[(size_t)i * H_ + h0 + tx];
        }
        // W: read coalesced over i, transpose via smem, store NEGATED * log2e
#pragma unroll
        for (int j = 0; j < 4; ++j) {
            int h = h0 + ty + j * 8;
            int i = i0 + tx;
            float v = 0.f;
            if (i < D_) v = W[(size_t)h * D_ + i] * -LOG2E;
            smem[(ty + j * 8) * 33 + tx] = v;
        }
        __syncthreads();
#pragma unroll
        for (int j = 0; j < 4; ++j) {
            int i = i0 + ty + j * 8;
            if (i < D_)
                VWf[vw_idx(i, h0 + tx, 1)] = smem[tx * 33 + ty + j * 8];
        }
    } else {
        float* xs = smem;          // [8][64]
        float* ws = smem + 512;    // [8][64]
        int idx = blockIdx.x - 800;
        int r   = idx >> 8;                       // 0..nseg-2
        int b0  = (idx & 15) * 64;
        int h0  = ((idx >> 4) & 15) * 64;
        int j0s = st[r], j1s = st[r + 1];

        const int tb = t >> 4, th = t & 15;       // 16x16, each 4b x 4h
        float acc[4][4];
#pragma unroll
        for (int bi = 0; bi < 4; ++bi)
#pragma unroll
            for (int hh = 0; hh < 4; ++hh) acc[bi][hh] = 0.f;

        const int xb = t >> 3;                    // 0..31
        const int xj = t & 7;                     // 0..7
        const int wh = t >> 1, wj = (t & 1) * 4;  // for t < 128

        for (int j0 = j0s; j0 < j1s; j0 += 8) {   // range lengths all %8 == 0
            float xv0 = px[(size_t)(b0 + xb) * D_ + j0 + xj];
            float xv1 = px[(size_t)(b0 + 32 + xb) * D_ + j0 + xj];
            float4 wv = make_float4(0, 0, 0, 0);
            if (t < 128) wv = *(const float4*)(W + (size_t)(h0 + wh) * D_ + j0 + wj);
            __syncthreads();
            xs[xj * 64 + xb]      = xv0;
            xs[xj * 64 + 32 + xb] = xv1;
            if (t < 128) {
                ws[(wj + 0) * 64 + wh] = wv.x * LOG2E;   // G stays POSITIVE domain
                ws[(wj + 1) * 64 + wh] = wv.y * LOG2E;
                ws[(wj + 2) * 64 + wh] = wv.z * LOG2E;
                ws[(wj + 3) * 64 + wh] = wv.w * LOG2E;
            }
            __syncthreads();
#pragma unroll
            for (int jj = 0; jj < 8; ++jj) {
                float4 xq = *(float4*)&xs[jj * 64 + tb * 4];
                float4 wq = *(float4*)&ws[jj * 64 + th * 4];
                float xa[4] = {xq.x, xq.y, xq.z, xq.w};
                float wa[4] = {wq.x, wq.y, wq.z, wq.w};
#pragma unroll
                for (int bi = 0; bi < 4; ++bi)
#pragma unroll
                    for (int hh = 0; hh < 4; ++hh)
                        acc[bi][hh] = fmaf(xa[bi], wa[hh], acc[bi][hh]);
            }
        }
        float* dst = G + (size_t)r * BH_;
#pragma unroll
        for (int bi = 0; bi < 4; ++bi) {
            float4 o = make_float4(acc[bi][0], acc[bi][1], acc[bi][2], acc[bi][3]);
            *(float4*)(dst + (size_t)(b0 + tb * 4 + bi) * H_ + h0 + th * 4) = o;
        }
    }
}

// ---------- DPP reduce: full 64-lane sum into lane 63 ----------
template <int CTRL>
__device__ __forceinline__ float dpp_add(float p) {
    int s = __builtin_amdgcn_update_dpp(0, __float_as_int(p), CTRL, 0xf, 0xf, true);
    return p + __int_as_float(s);
}
__device__ __forceinline__ float reduce64(float p) {
    p = dpp_add<0x111>(p);   // row_shr:1
    p = dpp_add<0x112>(p);   // row_shr:2
    p = dpp_add<0x114>(p);   // row_shr:4
    p = dpp_add<0x118>(p);   // row_shr:8
    p = dpp_add<0x142>(p);   // row_bcast:15 -> lane31 = sum(0..31), lane63 = sum(32..63)
    p = dpp_add<0x143>(p);   // row_bcast:31 -> lane63 = sum(0..63)
    return p;
}

// ---------- main scan v7: 1 wave = 1 row-segment, despilled ----------
__global__ __launch_bounds__(256, 4) void nade_main(
    const float* __restrict__ px,            // [B, D]
    const float* __restrict__ c,             // [H]
    const float* __restrict__ VWf,           // fp32 paired plane images
    const float* __restrict__ G,             // [nseg-1][B][H] (log2 domain, positive)
    const float* __restrict__ bias,          // [D]
    float* __restrict__ out,                 // [B, D]
    int nseg, int sshift)
{
    const int lane = threadIdx.x & 63;
    const int wid  = threadIdx.x >> 6;
    const int bid  = blockIdx.x;
    const int s    = bid & (nseg - 1);       // xcd = bid&7 -> one segment per XCD
    const int rb   = bid >> sshift;          // 0..255
    const int row  = rb * 4 + wid;

    const int* st = (nseg == 8) ? SEGTAB8 : SEGTAB4;
    const int i0s = st[s], i1s = st[s + 1];

    const int hA = lane * 8;
    const int hB = 512 + hA;

    // An = NEGATED log2-domain accumulator: sigma = 1/(1+2^An)
    v2f An[8];
    {
        float4 c0 = *(const float4*)(c + hA);
        float4 c1 = *(const float4*)(c + hA + 4);
        float4 c2 = *(const float4*)(c + hB);
        float4 c3 = *(const float4*)(c + hB + 4);
        An[0].x = -c0.x * LOG2E; An[0].y = -c2.x * LOG2E;
        An[1].x = -c0.y * LOG2E; An[1].y = -c2.y * LOG2E;
        An[2].x = -c0.z * LOG2E; An[2].y = -c2.z * LOG2E;
        An[3].x = -c0.w * LOG2E; An[3].y = -c2.w * LOG2E;
        An[4].x = -c1.x * LOG2E; An[4].y = -c3.x * LOG2E;
        An[5].x = -c1.y * LOG2E; An[5].y = -c3.y * LOG2E;
        An[6].x = -c1.z * LOG2E; An[6].y = -c3.z * LOG2E;
        An[7].x = -c1.w * LOG2E; An[7].y = -c3.w * LOG2E;
        for (int r = 0; r < s; ++r) {
            const float* gp = G + (size_t)r * BH_ + (size_t)row * H_;
            float4 g0 = *(const float4*)(gp + hA);
            float4 g1 = *(const float4*)(gp + hA + 4);
            float4 g2 = *(const float4*)(gp + hB);
            float4 g3 = *(const float4*)(gp + hB + 4);
            An[0].x -= g0.x; An[0].y -= g2.x;
            An[1].x -= g0.y; An[1].y -= g2.y;
            An[2].x -= g0.z; An[2].y -= g2.z;
            An[3].x -= g0.w; An[3].y -= g2.w;
            An[4].x -= g1.x; An[4].y -= g3.x;
            An[5].x -= g1.y; An[5].y -= g3.y;
            An[6].x -= g1.z; An[6].y -= g3.z;
            An[7].x -= g1.w; An[7].y -= g3.w;
        }
    }

    const float* xp = px + (size_t)row * D_;
    // image = 2048 floats; lane's plane-m slice at m*256 + lane*4 floats
    const float* vp = VWf + (size_t)i0s * 2048 + lane * 4;

    const v2f one = {1.f, 1.f};
    const v2f clamp15 = {15.f, 15.f};

    for (int ib = i0s; ib < i1s; ib += 4) {     // all segment lengths %4 == 0
        float4 xq = *(const float4*)(xp + ib);
        float xa[4] = {xq.x, xq.y, xq.z, xq.w};
        float pr[4];
#pragma unroll
        for (int j = 0; j < 4; ++j) {
            v2f xiv; xiv.x = xa[j]; xiv.y = xa[j];
            v2f a[4], qp[4];
#pragma unroll
            for (int kk = 0; kk < 4; ++kk) {    // pairs (2kk, 2kk+1): low liveness
                float4 Vq = *(const float4*)(vp + kk * 256);
                float4 Wq = *(const float4*)(vp + 1024 + kk * 256);
                const v2f* vv = (const v2f*)&Vq;
                const v2f* ww = (const v2f*)&Wq;
                const int k0 = 2 * kk, k1 = k0 + 1;
                v2f m0 = __builtin_elementwise_min(clamp15, An[k0]);
                v2f m1 = __builtin_elementwise_min(clamp15, An[k1]);
                v2f e0, e1;
                e0.x = __builtin_amdgcn_exp2f(m0.x);
                e0.y = __builtin_amdgcn_exp2f(m0.y);
                e1.x = __builtin_amdgcn_exp2f(m1.x);
                e1.y = __builtin_amdgcn_exp2f(m1.y);
                v2f q0 = one + e0;
                v2f q1 = one + e1;
                An[k0] = ww[0] * xiv + An[k0];  // v_pk_fma_f32 (W pre-negated)
                An[k1] = ww[1] * xiv + An[k1];
                a[kk]  = vv[0] * q1 + vv[1] * q0;
                qp[kk] = q0 * q1;
            }
            vp += 2048;
            v2f n0123 = a[0] * qp[1] + a[1] * qp[0];
            v2f n4567 = a[2] * qp[3] + a[3] * qp[2];
            v2f q0123 = qp[0] * qp[1], q4567 = qp[2] * qp[3];
            v2f d = q0123 * q4567;
            v2f n = n0123 * q4567 + n4567 * q0123;
            float p = fmaf(n.x, __builtin_amdgcn_rcpf(d.x),
                           n.y * __builtin_amdgcn_rcpf(d.y));
            pr[j] = reduce64(p);
        }
        float4 b4 = *(const float4*)(bias + ib);
        if (lane == 63) {
            float4 o = make_float4(pr[0] + b4.x, pr[1] + b4.y, pr[2] + b4.z, pr[3] + b4.w);
            *(float4*)(out + (size_t)row * D_ + ib) = o;
        }
    }
}

extern "C" void kernel_launch(void* const* d_in, const int* in_sizes, int n_in,
                              void* d_out, int out_size, void* d_ws, size_t ws_size,
                              hipStream_t stream) {
    const float* px   = (const float*)d_in[0];  // [B, D]
    const float* W    = (const float*)d_in[1];  // [H, D]
    const float* c    = (const float*)d_in[2];  // [H]
    const float* V    = (const float*)d_in[3];  // [D, H]
    const float* bias = (const float*)d_in[4];  // [D]
    float* out = (float*)d_out;                 // [B, D]

    float* VWf = (float*)d_ws;                                // 788*2048 f32 = 6.46 MB
    float* G   = (float*)((char*)d_ws + (size_t)788 * 8192);

    // 8-seg needs VWf + 7 G planes = 35.8 MB; fall back to verified 4-seg if tight
    const size_t need8 = (size_t)788 * 8192 + (size_t)7 * BH_ * 4;
    const int nseg   = (ws_size >= need8) ? 8 : 4;
    const int sshift = (nseg == 8) ? 3 : 2;

    // 800 pack blocks + (nseg-1) x 256 G-matmul blocks
    prep<<<dim3(800 + (nseg - 1) * 256), 256, 0, stream>>>(V, W, px, VWf, G, nseg);

    // nseg x 256 blocks x 4 waves; wave = (row, segment)
    nade_main<<<dim3(nseg * 256), 256, 0, stream>>>(px, c, VWf, G, bias, out, nseg, sshift);
}

// Round 10
// 306.844 us; speedup vs baseline: 1.3548x; 1.1104x over previous
//
#include <hip/hip_runtime.h>
#include <stdint.h>

#define B_ 1024
#define D_ 784
#define H_ 1024
#define BH_ (B_ * H_)
#define LOG2E 1.4426950408889634f

// Segments: {0,200,392,592,784}; G ranges: first 3 spans. 4-seg fixed (R9:
// 8-seg regressed main 250->262 via G-init HBM latency).
// main = v5 byte-identical (R7: 249.6us, VGPR 52, verified twice). R9 model
// closure: main is execution-width-bound (~57% of busy on trans pipe, pk=4cyc
// exec); its floor ~230-250us. This round reclaims the ~50us of prep+gaps.
// prep split for coalescing (old pack: 4B scattered writes -> sector
// amplification ~ dominant prep cost):
//   prep1: W-transpose -> WT[i][h] row-major (coalesced 128B writes, scaled
//          -log2e) + verified G-matmul unchanged.
//   prep2: per-image pack, thread t writes float4 {s[h],s[h+512],s[h+1],
//          s[h+513]} at linear f4 index t / t+256 -> fully coalesced; reads
//          hit L1-resident V/WT rows. Bit-identical VWf to v5 prep.
// ws: VWf [788][2048] f32 6.46 MB | G [3][B][H] 12.6 MB | WT [784][1024] 3.2 MB

typedef float v2f __attribute__((ext_vector_type(2)));

__device__ __forceinline__ int seg_bound(int s) {
    const int b[5] = {0, 200, 392, 592, 784};
    return b[s];
}

// ---------- prep1: W transpose (coalesced) + G matmul (verified) ----------
__global__ __launch_bounds__(256) void prep1(const float* __restrict__ W,
                                             const float* __restrict__ px,
                                             float* __restrict__ WT,
                                             float* __restrict__ G) {
    __shared__ float smem[1056];
    const int t = threadIdx.x;

    if (blockIdx.x < 800) {
        int i0 = (blockIdx.x % 25) * 32;
        int h0 = (blockIdx.x / 25) * 32;
        int tx = t & 31, ty = t >> 5;   // 32 x 8
        // read W coalesced over i, transpose via smem, write WT coalesced over h
#pragma unroll
        for (int j = 0; j < 4; ++j) {
            int h = h0 + ty + j * 8;
            int i = i0 + tx;
            float v = 0.f;
            if (i < D_) v = W[(size_t)h * D_ + i] * -LOG2E;
            smem[(ty + j * 8) * 33 + tx] = v;
        }
        __syncthreads();
#pragma unroll
        for (int j = 0; j < 4; ++j) {
            int i = i0 + ty + j * 8;
            if (i < D_)
                WT[(size_t)i * H_ + h0 + tx] = smem[tx * 33 + ty + j * 8];
        }
    } else {
        float* xs = smem;          // [8][64]
        float* ws = smem + 512;    // [8][64]
        int idx = blockIdx.x - 800;
        int r   = idx >> 8;                       // 0..2
        int b0  = (idx & 15) * 64;
        int h0  = ((idx >> 4) & 15) * 64;
        int j0s = seg_bound(r), j1s = seg_bound(r + 1);

        const int tb = t >> 4, th = t & 15;       // 16x16, each 4b x 4h
        float acc[4][4];
#pragma unroll
        for (int bi = 0; bi < 4; ++bi)
#pragma unroll
            for (int hh = 0; hh < 4; ++hh) acc[bi][hh] = 0.f;

        const int xb = t >> 3;                    // 0..31
        const int xj = t & 7;                     // 0..7
        const int wh = t >> 1, wj = (t & 1) * 4;  // for t < 128

        for (int j0 = j0s; j0 < j1s; j0 += 8) {   // range lengths all %8 == 0
            float xv0 = px[(size_t)(b0 + xb) * D_ + j0 + xj];
            float xv1 = px[(size_t)(b0 + 32 + xb) * D_ + j0 + xj];
            float4 wv = make_float4(0, 0, 0, 0);
            if (t < 128) wv = *(const float4*)(W + (size_t)(h0 + wh) * D_ + j0 + wj);
            __syncthreads();
            xs[xj * 64 + xb]      = xv0;
            xs[xj * 64 + 32 + xb] = xv1;
            if (t < 128) {
                ws[(wj + 0) * 64 + wh] = wv.x * LOG2E;   // G in POSITIVE log2 domain
                ws[(wj + 1) * 64 + wh] = wv.y * LOG2E;
                ws[(wj + 2) * 64 + wh] = wv.z * LOG2E;
                ws[(wj + 3) * 64 + wh] = wv.w * LOG2E;
            }
            __syncthreads();
#pragma unroll
            for (int jj = 0; jj < 8; ++jj) {
                float4 xq = *(float4*)&xs[jj * 64 + tb * 4];
                float4 wq = *(float4*)&ws[jj * 64 + th * 4];
                float xa[4] = {xq.x, xq.y, xq.z, xq.w};
                float wa[4] = {wq.x, wq.y, wq.z, wq.w};
#pragma unroll
                for (int bi = 0; bi < 4; ++bi)
#pragma unroll
                    for (int hh = 0; hh < 4; ++hh)
                        acc[bi][hh] = fmaf(xa[bi], wa[hh], acc[bi][hh]);
            }
        }
        float* dst = G + (size_t)r * BH_;
#pragma unroll
        for (int bi = 0; bi < 4; ++bi) {
            float4 o = make_float4(acc[bi][0], acc[bi][1], acc[bi][2], acc[bi][3]);
            *(float4*)(dst + (size_t)(b0 + tb * 4 + bi) * H_ + h0 + th * 4) = o;
        }
    }
}

// ---------- prep2: paired-image pack, fully coalesced writes ----------
// Image i = 512 float4; f4 index f: plane=f>>6 (0-3 V, 4-7 W), sp=plane&3,
// slot=f&63, h=slot*8+sp*2; float4 = {src[h], src[h+512], src[h+1], src[h+513]}.
// Matches v5's vw_idx layout bit-for-bit.
__global__ __launch_bounds__(256) void prep2(const float* __restrict__ V,
                                             const float* __restrict__ WT,
                                             float* __restrict__ VWf) {
    const int i = blockIdx.x;                // image 0..783
    const int t = threadIdx.x;               // 0..255
    const float* vsrc = V  + (size_t)i * H_;
    const float* wsrc = WT + (size_t)i * H_;
    const int sp   = (t >> 6) & 3;
    const int slot = t & 63;
    const int h    = slot * 8 + sp * 2;

    float4 a, b;
    a.x = vsrc[h];       a.y = vsrc[h + 512];
    a.z = vsrc[h + 1];   a.w = vsrc[h + 513];
    b.x = wsrc[h];       b.y = wsrc[h + 512];
    b.z = wsrc[h + 1];   b.w = wsrc[h + 513];

    float4* dst = (float4*)(VWf + (size_t)i * 2048);
    dst[t]       = a;    // V planes 0..3
    dst[t + 256] = b;    // W planes 4..7
}

// ---------- DPP reduce: full 64-lane sum into lane 63 ----------
template <int CTRL>
__device__ __forceinline__ float dpp_add(float p) {
    int s = __builtin_amdgcn_update_dpp(0, __float_as_int(p), CTRL, 0xf, 0xf, true);
    return p + __int_as_float(s);
}
__device__ __forceinline__ float reduce64(float p) {
    p = dpp_add<0x111>(p);   // row_shr:1
    p = dpp_add<0x112>(p);   // row_shr:2
    p = dpp_add<0x114>(p);   // row_shr:4
    p = dpp_add<0x118>(p);   // row_shr:8
    p = dpp_add<0x142>(p);   // row_bcast:15 -> lane31 = sum(0..31), lane63 = sum(32..63)
    p = dpp_add<0x143>(p);   // row_bcast:31 -> lane63 = sum(0..63)
    return p;
}

// Fused dual 8-wide rational tree on memory-native float2 pairs.
// An is the NEGATED log2-domain accumulator: sigma = 1/(1+2^An).
// d = prod q, n = sum v_k * prod_{j!=k} q_j per component; clamp 15 keeps d <= 2^120.
__device__ __forceinline__ void tree16(v2f (&An)[8], const float4 (&Va)[4], const float4 (&Wa)[4],
                                       float xi, v2f& n, v2f& d) {
    const v2f* va = (const v2f*)&Va[0];
    const v2f* wa = (const v2f*)&Wa[0];
    const v2f one = {1.f, 1.f};
    const v2f clamp15 = {15.f, 15.f};
    v2f xiv; xiv.x = xi; xiv.y = xi;
    v2f q[8];
#pragma unroll
    for (int k = 0; k < 8; ++k) {
        v2f m = __builtin_elementwise_min(clamp15, An[k]);   // v_pk_min_f32
        v2f e;
        e.x = __builtin_amdgcn_exp2f(m.x);
        e.y = __builtin_amdgcn_exp2f(m.y);
        q[k] = one + e;                 // v_pk_add_f32
        An[k] = wa[k] * xiv + An[k];    // v_pk_fma_f32 (W pre-negated)
    }
    v2f a01 = va[0] * q[1] + va[1] * q[0];
    v2f a23 = va[2] * q[3] + va[3] * q[2];
    v2f a45 = va[4] * q[5] + va[5] * q[4];
    v2f a67 = va[6] * q[7] + va[7] * q[6];
    v2f q01 = q[0] * q[1], q23 = q[2] * q[3];
    v2f q45 = q[4] * q[5], q67 = q[6] * q[7];
    v2f n0123 = a01 * q23 + a23 * q01;
    v2f n4567 = a45 * q67 + a67 * q45;
    v2f q0123 = q01 * q23, q4567 = q45 * q67;
    d = q0123 * q4567;
    n = n0123 * q4567 + n4567 * q0123;
}

// ---------- main scan (v5, verified 249.6us): 1 wave = 1 row ----------
__global__ __launch_bounds__(256, 4) void nade_main(
    const float* __restrict__ px,            // [B, D]
    const float* __restrict__ c,             // [H]
    const float* __restrict__ VWf,           // fp32 paired plane images
    const float* __restrict__ G,             // [3][B][H] (log2 domain, positive)
    const float* __restrict__ bias,          // [D]
    float* __restrict__ out)                 // [B, D]
{
    const int lane = threadIdx.x & 63;
    const int wid  = threadIdx.x >> 6;
    const int bid  = blockIdx.x;             // 0..1023
    const int s    = (bid >> 1) & 3;         // xcd = bid&7 -> one segment per XCD
    const int rb   = ((bid >> 3) << 1) | (bid & 1);   // 0..255
    const int row  = rb * 4 + wid;

    const int i0s = seg_bound(s), i1s = seg_bound(s + 1);

    const int hA = lane * 8;
    const int hB = 512 + hA;

    v2f An[8];
    {
        float4 c0 = *(const float4*)(c + hA);
        float4 c1 = *(const float4*)(c + hA + 4);
        float4 c2 = *(const float4*)(c + hB);
        float4 c3 = *(const float4*)(c + hB + 4);
        An[0].x = -c0.x * LOG2E; An[0].y = -c2.x * LOG2E;
        An[1].x = -c0.y * LOG2E; An[1].y = -c2.y * LOG2E;
        An[2].x = -c0.z * LOG2E; An[2].y = -c2.z * LOG2E;
        An[3].x = -c0.w * LOG2E; An[3].y = -c2.w * LOG2E;
        An[4].x = -c1.x * LOG2E; An[4].y = -c3.x * LOG2E;
        An[5].x = -c1.y * LOG2E; An[5].y = -c3.y * LOG2E;
        An[6].x = -c1.z * LOG2E; An[6].y = -c3.z * LOG2E;
        An[7].x = -c1.w * LOG2E; An[7].y = -c3.w * LOG2E;
        for (int r = 0; r < s; ++r) {
            const float* gp = G + (size_t)r * BH_ + (size_t)row * H_;
            float4 g0 = *(const float4*)(gp + hA);
            float4 g1 = *(const float4*)(gp + hA + 4);
            float4 g2 = *(const float4*)(gp + hB);
            float4 g3 = *(const float4*)(gp + hB + 4);
            An[0].x -= g0.x; An[0].y -= g2.x;
            An[1].x -= g0.y; An[1].y -= g2.y;
            An[2].x -= g0.z; An[2].y -= g2.z;
            An[3].x -= g0.w; An[3].y -= g2.w;
            An[4].x -= g1.x; An[4].y -= g3.x;
            An[5].x -= g1.y; An[5].y -= g3.y;
            An[6].x -= g1.z; An[6].y -= g3.z;
            An[7].x -= g1.w; An[7].y -= g3.w;
        }
    }

    const float* xp = px + (size_t)row * D_;
    // image = 2048 floats; lane's plane-m slice at m*256 + lane*4 floats
    const float* vp = VWf + (size_t)i0s * 2048 + lane * 4;

    // prologue: load step i0s into current buffers
    float4 VaC[4], WaC[4];
#pragma unroll
    for (int u = 0; u < 4; ++u) {
        VaC[u] = *(const float4*)(vp + u * 256);
        WaC[u] = *(const float4*)(vp + 1024 + u * 256);
    }
    vp += 2048;
    float4 xq = *(const float4*)(xp + i0s);

    for (int ib = i0s; ib < i1s; ib += 4) {     // all segment lengths %4 == 0
        int xb = (ib + 4 < i1s) ? (ib + 4) : i0s;
        float4 xq_n = *(const float4*)(xp + xb);
        float xa[4] = {xq.x, xq.y, xq.z, xq.w};
        float pr[4];
#pragma unroll
        for (int j = 0; j < 4; ++j) {
            float4 VaN[4], WaN[4];               // prefetch next step (images padded past 784)
#pragma unroll
            for (int u = 0; u < 4; ++u) {
                VaN[u] = *(const float4*)(vp + u * 256);
                WaN[u] = *(const float4*)(vp + 1024 + u * 256);
            }
            vp += 2048;
            v2f n, d;
            tree16(An, VaC, WaC, xa[j], n, d);
            float p = fmaf(n.x, __builtin_amdgcn_rcpf(d.x),
                           n.y * __builtin_amdgcn_rcpf(d.y));
            pr[j] = reduce64(p);
#pragma unroll
            for (int u = 0; u < 4; ++u) { VaC[u] = VaN[u]; WaC[u] = WaN[u]; }
        }
        float4 b4 = *(const float4*)(bias + ib);
        if (lane == 63) {
            float4 o = make_float4(pr[0] + b4.x, pr[1] + b4.y, pr[2] + b4.z, pr[3] + b4.w);
            *(float4*)(out + (size_t)row * D_ + ib) = o;
        }
        xq = xq_n;
    }
}

extern "C" void kernel_launch(void* const* d_in, const int* in_sizes, int n_in,
                              void* d_out, int out_size, void* d_ws, size_t ws_size,
                              hipStream_t stream) {
    const float* px   = (const float*)d_in[0];  // [B, D]
    const float* W    = (const float*)d_in[1];  // [H, D]
    const float* c    = (const float*)d_in[2];  // [H]
    const float* V    = (const float*)d_in[3];  // [D, H]
    const float* bias = (const float*)d_in[4];  // [D]
    float* out = (float*)d_out;                 // [B, D]

    float* VWf = (float*)d_ws;                                 // 788*2048 f32 = 6.46 MB
    float* G   = (float*)((char*)d_ws + (size_t)788 * 8192);   // [3][B][H] 12.6 MB
    float* WT  = (float*)((char*)d_ws + (size_t)788 * 8192 + (size_t)3 * BH_ * 4);  // 3.2 MB

    // prep1: 800 W-transpose blocks + 3 x 256 G-matmul blocks
    prep1<<<dim3(1568), 256, 0, stream>>>(W, px, WT, G);
    // prep2: 784 image-pack blocks (coalesced)
    prep2<<<dim3(784), 256, 0, stream>>>(V, WT, VWf);
    // main: 1024 blocks x 4 waves; block = (segment, 4 consecutive rows)
    nade_main<<<dim3(1024), 256, 0, stream>>>(px, c, VWf, G, bias, out);
}